// Round 11
// baseline (182.973 us; speedup 1.0000x reference)
//
#include <hip/hip_runtime.h>

typedef float f32x4 __attribute__((ext_vector_type(4)));
typedef short bf16x8 __attribute__((ext_vector_type(8)));   // 8 bf16 in 4 VGPRs (MFMA A/B operand)
typedef short bf16x4 __attribute__((ext_vector_type(4)));   // 4 bf16 in 2 VGPRs (16x16x16 operand)
typedef unsigned short u16x4 __attribute__((ext_vector_type(4)));

#define NS 8192
#define NB 16
#define NE 128
#define GS 4   // s-values per block in KV kernel / legacy kernel
// log2(e)/sqrt(8192), folded into Wk/bk by the prelude
#define SCALE_K (1.4426950408889634f / 90.50966799187809f)

// K=16 scores MFMA (no zero-padding waste) if the legacy builtin exists on this ROCm.
#if __has_builtin(__builtin_amdgcn_mfma_f32_16x16x16bf16_1k)
#define HAS_MFMA16 1
#else
#define HAS_MFMA16 0
#endif

// Pack two f32 -> two bf16 RNE-ish (round-half-up via +0x8000; perm takes high halves).
__device__ __forceinline__ unsigned pack_bf16_rn(float lo, float hi) {
  union { float f; unsigned u; } a, b; a.f = lo; b.f = hi;
  return __builtin_amdgcn_perm(b.u + 0x8000u, a.u + 0x8000u, 0x07060302u);
}
// Truncating pack (bias cancels in p/l since l is summed from these same bf16 values)
__device__ __forceinline__ unsigned pack_bf16_tr(float lo, float hi) {
  union { float f; unsigned u; } a, b; a.f = lo; b.f = hi;
  return __builtin_amdgcn_perm(b.u, a.u, 0x07060302u);
}
__device__ __forceinline__ bf16x8 frag_from_f32(const float* p) {
  f32x4 lo = *(const f32x4*)p;
  f32x4 hi = *(const f32x4*)(p + 4);
  union { bf16x8 v; unsigned u[4]; } r;
  r.u[0] = pack_bf16_rn(lo[0], lo[1]);
  r.u[1] = pack_bf16_rn(lo[2], lo[3]);
  r.u[2] = pack_bf16_rn(hi[0], hi[1]);
  r.u[3] = pack_bf16_rn(hi[2], hi[3]);
  return r.v;
}
__device__ __forceinline__ u16x4 pack4_rn(f32x4 v) {
  union { u16x4 s; unsigned u[2]; } r;
  r.u[0] = pack_bf16_rn(v[0], v[1]);
  r.u[1] = pack_bf16_rn(v[2], v[3]);
  return r.s;
}
__device__ __forceinline__ u16x4 pack4_tr(f32x4 v) {
  union { u16x4 s; unsigned u[2]; } r;
  r.u[0] = pack_bf16_tr(v[0], v[1]);
  r.u[1] = pack_bf16_tr(v[2], v[3]);
  return r.s;
}

// ---------- prelude: W -> bf16 fragments in d_ws (once per launch) ----------
// wsW layout: [mat(2)][ntile(8)][ks(4)][lane(64)][8 shorts]  -> frag load = 1 coalesced b128
// Wk, bk pre-scaled by SCALE_K so softmax is exp2(score) with no per-element multiply.
__global__ __launch_bounds__(256)
void nsa_prep(const float* __restrict__ Wk, const float* __restrict__ bk,
              const float* __restrict__ Wv, const float* __restrict__ bv,
              unsigned short* __restrict__ wsW, float* __restrict__ wsB)
{
  const int t    = blockIdx.x * 256 + threadIdx.x;   // 0..4095
  const int lane = t & 63, ks = (t >> 6) & 3, nt = (t >> 8) & 7, mat = (t >> 11) & 1;
  const int q = lane >> 4, ln = lane & 15;
  const float sc = mat ? 1.0f : SCALE_K;
  const float* W = (mat ? Wv : Wk) + (nt * 16 + ln) * NE + ks * 32 + q * 8;
  union { bf16x8 v; unsigned u[4]; } r;
  #pragma unroll
  for (int i = 0; i < 4; ++i)
    r.u[i] = pack_bf16_rn(W[2 * i] * sc, W[2 * i + 1] * sc);
  *(bf16x8*)(wsW + t * 8) = r.v;
  if (t < NE)          wsB[t] = bk[t] * SCALE_K;
  else if (t < 2 * NE) wsB[t] = bv[t - NE];
}

// ================== SPLIT PATH ==================
// nsa_kv: stage x (R5 structure) + KV GEMM; store K,V as bf16 MFMA FRAGMENTS:
// frag[s][tile(8)][lane(64)][4 shorts]. Lane (q,ln)'s u16x4 = M[b=q*4+r][e=tile*16+ln]
// -- exactly the b64 operand nsa_attn loads back (same lane -> identity mapping,
// no swizzle, 512B coalesced per instruction on both sides).
__global__ __launch_bounds__(512, 4)
void nsa_kv(const float* __restrict__ x,
            const unsigned short* __restrict__ wsW,
            const float* __restrict__ wsB,
            unsigned short* __restrict__ kfG,
            unsigned short* __restrict__ vfG)
{
  __shared__ __align__(16) unsigned short xs[GS * NB * NE];   // 16 KiB x-stage (bf16)

  const int tid  = threadIdx.x;
  const int wave = tid >> 6;          // 0..7
  const int lane = tid & 63;
  const int q    = lane >> 4;
  const int ln   = lane & 15;
  const int s0   = blockIdx.x * GS;
  const int smt  = wave & 3;          // s this wave stages
  const int h    = wave >> 2;         // row half staged

  // x staging: global -> bf16 -> xs (xs layout [s][b][granule gr=((ks*4+q)^b)&15][8])
  {
    const int c  = lane >> 5;
    const int sq = (lane >> 3) & 3;
    const int bl = lane & 7;
    const int b  = h * 8 + bl;
    const float* xp = x + ((s0 + smt) * NB + b) * NE + c * 64 + sq * 8;
    #pragma unroll
    for (int ksp = 0; ksp < 2; ++ksp) {
      const int ks = c * 2 + ksp;
      bf16x8 v = frag_from_f32(xp + ksp * 32);
      const int gr = ((ks * 4 + sq) ^ b) & 15;
      *(bf16x8*)&xs[smt * 2048 + b * 128 + gr * 8] = v;
    }
  }
  __syncthreads();

  // KV: wave w -> n-tile nt=w for all GS s, both mats; store frags to global.
  bf16x8 wf[2][4];
  float  bias[2];
  #pragma unroll
  for (int mat = 0; mat < 2; ++mat) {
    #pragma unroll
    for (int ks = 0; ks < 4; ++ks)
      wf[mat][ks] = *(const bf16x8*)(wsW + (((mat * 8 + wave) * 4 + ks) * 64 + lane) * 8);
    bias[mat] = wsB[mat * NE + wave * 16 + ln];
  }

  #pragma unroll
  for (int i = 0; i < GS; ++i) {
    const int mt = (smt + 1 + i) & (GS - 1);
    bf16x8 xf[4];
    #pragma unroll
    for (int ks = 0; ks < 4; ++ks) {
      const int gr = ((ks * 4 + q) ^ ln) & 15;
      xf[ks] = *(const bf16x8*)&xs[mt * 2048 + ln * 128 + gr * 8];
    }
    #pragma unroll
    for (int mat = 0; mat < 2; ++mat) {
      f32x4 acc = { bias[mat], bias[mat], bias[mat], bias[mat] };
      #pragma unroll
      for (int ks = 0; ks < 4; ++ks)
        acc = __builtin_amdgcn_mfma_f32_16x16x32_bf16(xf[ks], wf[mat][ks], acc, 0, 0, 0);
      unsigned short* dst = mat ? vfG : kfG;
      *(u16x4*)&dst[(((s0 + mt) * 8 + wave) * 64 + lane) * 4] = pack4_rn(acc);
    }
  }
}

// nsa_attn: ONE WAVE PER s, zero barriers, private 4KB P LDS slice per wave.
// Math identical to the verified R7-R9 attention phase (same P swizzle formulas,
// same ones-MFMA denominator); operands come from the frag arrays + x.
__global__ __launch_bounds__(256, 4)
void nsa_attn(const float* __restrict__ x,
              const unsigned short* __restrict__ kfG,
              const unsigned short* __restrict__ vfG,
              float* __restrict__ out)
{
  __shared__ __align__(16) unsigned short plds[4 * NB * NE];   // 16 KiB: 4KB per wave

  const int tid  = threadIdx.x;
  const int wave = tid >> 6;
  const int lane = tid & 63;
  const int q    = lane >> 4;
  const int ln   = lane & 15;
  const int s    = blockIdx.x * 4 + wave;
  unsigned short* pw = &plds[wave * (NB * NE)];

#if HAS_MFMA16
  bf16x4 vf[8], kc[8];
  #pragma unroll
  for (int t = 0; t < 8; ++t)
    vf[t] = *(const bf16x4*)&vfG[((s * 8 + t) * 64 + lane) * 4];
  #pragma unroll
  for (int t = 0; t < 8; ++t)
    kc[t] = *(const bf16x4*)&kfG[((s * 8 + t) * 64 + lane) * 4];
#else
  bf16x8 vf[8], kc[8];   // upper K-half zero (A zero there -> B don't-care)
  #pragma unroll
  for (int t = 0; t < 8; ++t) {
    union { bf16x8 w; bf16x4 h[2]; } a, b;
    a.h[0] = *(const bf16x4*)&vfG[((s * 8 + t) * 64 + lane) * 4];
    a.h[1] = (bf16x4){0, 0, 0, 0};
    b.h[0] = *(const bf16x4*)&kfG[((s * 8 + t) * 64 + lane) * 4];
    b.h[1] = (bf16x4){0, 0, 0, 0};
    vf[t] = a.w; kc[t] = b.w;
  }
#endif

  bf16x8 xf[4];   // PV A-operand: x[b=ln][f], packed from f32
  #pragma unroll
  for (int ks = 0; ks < 4; ++ks)
    xf[ks] = frag_from_f32(x + (s * NB + ln) * NE + ks * 32 + q * 8);

  union { bf16x8 v; unsigned u[4]; } onesu;
  #pragma unroll
  for (int i = 0; i < 4; ++i) onesu.u[i] = 0x3F803F80u;
  const bf16x8 ones = onesu.v;

  #pragma unroll 2
  for (int eb = 0; eb < 8; ++eb) {
    // scores -> exp2 -> packed P (registers)
    u16x4 pp[8];
    #pragma unroll
    for (int mt = 0; mt < 8; ++mt) {
      const f32x4 z = { 0.f, 0.f, 0.f, 0.f };
#if HAS_MFMA16
      f32x4 sc = __builtin_amdgcn_mfma_f32_16x16x16bf16_1k(vf[mt], kc[eb], z, 0, 0, 0);
#else
      f32x4 sc = __builtin_amdgcn_mfma_f32_16x16x32_bf16(vf[mt], kc[eb], z, 0, 0, 0);
#endif
      f32x4 p;
      #pragma unroll
      for (int r = 0; r < 4; ++r) p[r] = __builtin_amdgcn_exp2f(sc[r]);
      pp[mt] = pack4_tr(p);
    }
    // P -> LDS (conflict-free swizzle, verified R7-R9)
    #pragma unroll
    for (int mt = 0; mt < 8; ++mt) {
      const int cw = ((q & 1) << 2) | (((((mt << 1) | (q >> 1)) ^ ln) & 15) << 3);
      *(u16x4*)&pw[ln * 128 + cw] = pp[mt];
    }
    // PV + denominator
    f32x4 oacc = { 0.f, 0.f, 0.f, 0.f };
    f32x4 lacc = { 0.f, 0.f, 0.f, 0.f };
    #pragma unroll
    for (int k = 0; k < 4; ++k) {
      const int cr = ((((k << 2) | q) ^ ln) & 15) << 3;
      const bf16x8 pf = *(const bf16x8*)&pw[ln * 128 + cr];
      oacc = __builtin_amdgcn_mfma_f32_16x16x32_bf16(xf[k], pf, oacc, 0, 0, 0);
      lacc = __builtin_amdgcn_mfma_f32_16x16x32_bf16(ones,  pf, lacc, 0, 0, 0);
    }
    const float inv_l = __builtin_amdgcn_rcpf(lacc[0]);
    const int e = eb * 16 + ln;
    #pragma unroll
    for (int r = 0; r < 4; ++r)
      out[(s * NB + q * 4 + r) * NE + e] = oacc[r] * inv_l;
  }
}

// ================== LEGACY FUSED PATH (R9, measured 42-43us) ==================
__global__ __launch_bounds__(512, 4)
void nsa_fused(const float* __restrict__ x,
               const unsigned short* __restrict__ wsW,
               const float* __restrict__ wsB,
               float* __restrict__ out)
{
  __shared__ __align__(16) unsigned short kt[2 * GS * NE * 16];   // 32 KiB
  __shared__ __align__(16) unsigned short xs[GS * NB * NE];       // 16 KiB
#if !HAS_MFMA16
  __shared__ __align__(16) unsigned short zbuf[32];
#endif

  const int tid  = threadIdx.x;
  const int wave = tid >> 6;
  const int lane = tid & 63;
  const int q    = lane >> 4;
  const int ln   = lane & 15;
  const int g    = (ln >> 2) & 1;
  const int s0   = blockIdx.x * GS;
  const int smt  = wave & 3;
  const int h    = wave >> 2;

#if !HAS_MFMA16
  if (tid < 32) zbuf[tid] = 0;
#endif

  {
    const int c  = lane >> 5;
    const int sq = (lane >> 3) & 3;
    const int bl = lane & 7;
    const int b  = h * 8 + bl;
    const float* xp = x + ((s0 + smt) * NB + b) * NE + c * 64 + sq * 8;
    #pragma unroll
    for (int ksp = 0; ksp < 2; ++ksp) {
      const int ks = c * 2 + ksp;
      bf16x8 v = frag_from_f32(xp + ksp * 32);
      const int gr = ((ks * 4 + sq) ^ b) & 15;
      *(bf16x8*)&xs[smt * 2048 + b * 128 + gr * 8] = v;
    }
  }
  __syncthreads();

  bf16x8 xf[4];
  {
    bf16x8 wf[2][4];
    float  bias[2];
    #pragma unroll
    for (int mat = 0; mat < 2; ++mat) {
      #pragma unroll
      for (int ks = 0; ks < 4; ++ks)
        wf[mat][ks] = *(const bf16x8*)(wsW + (((mat * 8 + wave) * 4 + ks) * 64 + lane) * 8);
      bias[mat] = wsB[mat * NE + wave * 16 + ln];
    }
    const int o = (((q >> 1) ^ g) << 3) + ((q & 1) << 2);
    const int e = wave * 16 + ln;
    #pragma unroll
    for (int i = 0; i < GS; ++i) {
      const int mt = (smt + 1 + i) & (GS - 1);
      #pragma unroll
      for (int ks = 0; ks < 4; ++ks) {
        const int gr = ((ks * 4 + q) ^ ln) & 15;
        xf[ks] = *(const bf16x8*)&xs[mt * 2048 + ln * 128 + gr * 8];
      }
      #pragma unroll
      for (int mat = 0; mat < 2; ++mat) {
        f32x4 acc = { bias[mat], bias[mat], bias[mat], bias[mat] };
        #pragma unroll
        for (int ks = 0; ks < 4; ++ks)
          acc = __builtin_amdgcn_mfma_f32_16x16x32_bf16(xf[ks], wf[mat][ks], acc, 0, 0, 0);
        *(u16x4*)&kt[((mat * GS + mt) * NE + e) * 16 + o] = pack4_rn(acc);
      }
    }
  }
  __syncthreads();

#if HAS_MFMA16
  const int ov = (((q >> 1) ^ g) << 3) + ((q & 1) << 2);
  bf16x4 vf[8];
  #pragma unroll
  for (int mt = 0; mt < 8; ++mt)
    vf[mt] = *(const bf16x4*)&kt[((GS + smt) * NE + mt * 16 + ln) * 16 + ov];
  bf16x4 kcs[4];
  #pragma unroll
  for (int e2 = 0; e2 < 4; ++e2)
    kcs[e2] = *(const bf16x4*)&kt[(smt * NE + (h * 4 + e2) * 16 + ln) * 16 + ov];
#else
  const int ro = ((q ^ g) & 1) << 3;
  bf16x8 vf[8];
  #pragma unroll
  for (int mt = 0; mt < 8; ++mt) {
    const unsigned short* src =
        (q < 2) ? &kt[((GS + smt) * NE + mt * 16 + ln) * 16 + ro] : zbuf;
    vf[mt] = *(const bf16x8*)src;
  }
  bf16x8 kcs[4];
  #pragma unroll
  for (int e2 = 0; e2 < 4; ++e2)
    kcs[e2] = *(const bf16x8*)&kt[(smt * NE + (h * 4 + e2) * 16 + ln) * 16 + ro];
#endif
  __syncthreads();

  {
    const int sw = s0 + smt;
    unsigned short* pw = h ? &xs[smt * 2048] : &kt[(GS + smt) * NE * 16];
    union { bf16x8 v; unsigned u[4]; } onesu;
    #pragma unroll
    for (int i = 0; i < 4; ++i) onesu.u[i] = 0x3F803F80u;
    const bf16x8 ones = onesu.v;

    #pragma unroll
    for (int ebi = 0; ebi < 4; ++ebi) {
      const int eb = h * 4 + ebi;
      u16x4 pp[8];
      #pragma unroll
      for (int mt = 0; mt < 8; ++mt) {
        const f32x4 z = { 0.f, 0.f, 0.f, 0.f };
#if HAS_MFMA16
        f32x4 sc = __builtin_amdgcn_mfma_f32_16x16x16bf16_1k(vf[mt], kcs[ebi], z, 0, 0, 0);
#else
        f32x4 sc = __builtin_amdgcn_mfma_f32_16x16x32_bf16(vf[mt], kcs[ebi], z, 0, 0, 0);
#endif
        f32x4 p;
        #pragma unroll
        for (int r = 0; r < 4; ++r) p[r] = __builtin_amdgcn_exp2f(sc[r]);
        pp[mt] = pack4_tr(p);
      }
      #pragma unroll
      for (int mt = 0; mt < 8; ++mt) {
        const int cw = ((q & 1) << 2) | (((((mt << 1) | (q >> 1)) ^ ln) & 15) << 3);
        *(u16x4*)&pw[ln * 128 + cw] = pp[mt];
      }
      f32x4 oacc = { 0.f, 0.f, 0.f, 0.f };
      f32x4 lacc = { 0.f, 0.f, 0.f, 0.f };
      #pragma unroll
      for (int k = 0; k < 4; ++k) {
        const int cr = ((((k << 2) | q) ^ ln) & 15) << 3;
        const bf16x8 pf = *(const bf16x8*)&pw[ln * 128 + cr];
        oacc = __builtin_amdgcn_mfma_f32_16x16x32_bf16(xf[k], pf, oacc, 0, 0, 0);
        lacc = __builtin_amdgcn_mfma_f32_16x16x32_bf16(ones,  pf, lacc, 0, 0, 0);
      }
      const float inv_l = __builtin_amdgcn_rcpf(lacc[0]);
      const int e = eb * 16 + ln;
      #pragma unroll
      for (int r = 0; r < 4; ++r)
        out[(sw * NB + q * 4 + r) * NE + e] = oacc[r] * inv_l;
    }
  }
}

extern "C" void kernel_launch(void* const* d_in, const int* in_sizes, int n_in,
                              void* d_out, int out_size, void* d_ws, size_t ws_size,
                              hipStream_t stream)
{
  const float* x  = (const float*)d_in[0];
  const float* Wk = (const float*)d_in[1];
  const float* bk = (const float*)d_in[2];
  const float* Wv = (const float*)d_in[3];
  const float* bv = (const float*)d_in[4];
  float* o = (float*)d_out;

  unsigned short* wsW = (unsigned short*)d_ws;                  // 64 KiB
  float*          wsB = (float*)((char*)d_ws + 64 * 1024);      // 1 KiB

  hipLaunchKernelGGL(nsa_prep, dim3(16), dim3(256), 0, stream, Wk, bk, Wv, bv, wsW, wsB);

  // KV fragment arrays: 32 MiB each, at +1 MiB / +33 MiB in the workspace.
  const size_t frag_bytes = (size_t)NS * 8 * 64 * 4 * 2;        // 32 MiB
  const size_t need = (1ull << 20) + 2 * frag_bytes;            // 65 MiB
  if (ws_size >= need) {
    unsigned short* kfG = (unsigned short*)((char*)d_ws + (1ull << 20));
    unsigned short* vfG = (unsigned short*)((char*)d_ws + (1ull << 20) + frag_bytes);
    hipLaunchKernelGGL(nsa_kv,   dim3(NS / GS), dim3(512), 0, stream, x, wsW, wsB, kfG, vfG);
    hipLaunchKernelGGL(nsa_attn, dim3(NS / 4),  dim3(256), 0, stream, x, kfG, vfG, o);
  } else {
    hipLaunchKernelGGL(nsa_fused, dim3(NS / GS), dim3(512), 0, stream, x, wsW, wsB, o);
  }
}